// Round 1
// baseline (150.235 us; speedup 1.0000x reference)
//
#include <hip/hip_runtime.h>
#include <hip/hip_bf16.h>

#define EPS 1e-6f

constexpr int B = 64;
constexpr int NPB = 512 * 512;           // elements per batch = 262144
constexpr int BLOCKS_PER_BATCH = 32;
constexpr int THREADS = 256;
constexpr int CHUNK = NPB / BLOCKS_PER_BATCH;   // 8192 elements per block

__device__ __forceinline__ float waveReduce(float v) {
    #pragma unroll
    for (int off = 32; off > 0; off >>= 1) v += __shfl_down(v, off, 64);
    return v;
}

// Kernel 1: per-batch partial sums of (Sp, St, S = sum t*(log t - log p))
__global__ __launch_bounds__(THREADS) void kl_partial(
        const float* __restrict__ pred, const float* __restrict__ truem,
        float* __restrict__ ws) {
    const int b   = blockIdx.x / BLOCKS_PER_BATCH;
    const int blk = blockIdx.x % BLOCKS_PER_BATCH;
    const size_t base = (size_t)b * NPB + (size_t)blk * CHUNK;

    const float4* p4 = (const float4*)(pred + base);
    const float4* t4 = (const float4*)(truem + base);
    const int n4 = CHUNK / 4;   // 2048 float4 per block per input

    float sp = 0.f, st = 0.f, s = 0.f;
    for (int i = threadIdx.x; i < n4; i += THREADS) {
        float4 p = p4[i];
        float4 t = t4[i];
        float px = p.x + EPS, py = p.y + EPS, pz = p.z + EPS, pw = p.w + EPS;
        float tx = t.x + EPS, ty = t.y + EPS, tz = t.z + EPS, tw = t.w + EPS;
        sp += (px + py) + (pz + pw);
        st += (tx + ty) + (tz + tw);
        s  += tx * (__logf(tx) - __logf(px));
        s  += ty * (__logf(ty) - __logf(py));
        s  += tz * (__logf(tz) - __logf(pz));
        s  += tw * (__logf(tw) - __logf(pw));
    }

    sp = waveReduce(sp);
    st = waveReduce(st);
    s  = waveReduce(s);

    __shared__ float red[3][THREADS / 64];
    const int wave = threadIdx.x >> 6;
    const int lane = threadIdx.x & 63;
    if (lane == 0) { red[0][wave] = sp; red[1][wave] = st; red[2][wave] = s; }
    __syncthreads();
    if (threadIdx.x == 0) {
        float a0 = 0.f, a1 = 0.f, a2 = 0.f;
        #pragma unroll
        for (int w = 0; w < THREADS / 64; ++w) {
            a0 += red[0][w]; a1 += red[1][w]; a2 += red[2][w];
        }
        atomicAdd(&ws[b],         a0);   // Sp
        atomicAdd(&ws[B + b],     a1);   // St
        atomicAdd(&ws[2 * B + b], a2);   // S
    }
}

// Kernel 2: combine 64 per-batch triples, write mean KL
__global__ __launch_bounds__(64) void kl_final(
        const float* __restrict__ ws, float* __restrict__ out) {
    const int b = threadIdx.x;   // 0..63, one wave
    float Sp = ws[b];
    float St = ws[B + b];
    float S  = ws[2 * B + b];
    float kl = S / St + logf(Sp / St);
    kl = waveReduce(kl);
    if (b == 0) out[0] = kl * (1.0f / B);
}

extern "C" void kernel_launch(void* const* d_in, const int* in_sizes, int n_in,
                              void* d_out, int out_size, void* d_ws, size_t ws_size,
                              hipStream_t stream) {
    const float* pred = (const float*)d_in[0];
    const float* truem = (const float*)d_in[1];
    float* out = (float*)d_out;
    float* ws = (float*)d_ws;

    // ws is re-poisoned to 0xAA before every call — zero the accumulators.
    hipMemsetAsync(ws, 0, 3 * B * sizeof(float), stream);

    kl_partial<<<B * BLOCKS_PER_BATCH, THREADS, 0, stream>>>(pred, truem, ws);
    kl_final<<<1, 64, 0, stream>>>(ws, out);
}

// Round 2
// 146.208 us; speedup vs baseline: 1.0275x; 1.0275x over previous
//
#include <hip/hip_runtime.h>
#include <hip/hip_bf16.h>

#define EPS 1e-6f

constexpr int B = 64;
constexpr int NPB = 512 * 512;                    // elements per batch = 262144
constexpr int BLOCKS_PER_BATCH = 32;
constexpr int NBLK = B * BLOCKS_PER_BATCH;        // 2048 blocks total
constexpr int THREADS = 256;
constexpr int CHUNK = NPB / BLOCKS_PER_BATCH;     // 8192 elements per block
constexpr int V4_PER_THREAD = CHUNK / 4 / THREADS; // 8 float4 per thread per input

__device__ __forceinline__ float waveReduce(float v) {
    #pragma unroll
    for (int off = 32; off > 0; off >>= 1) v += __shfl_down(v, off, 64);
    return v;
}

// Kernel 1: per-block partial sums of (Sp, St, S = sum t*(log t - log p)).
// All 16 float4 loads issued before any compute -> 16 in-flight VMEM ops/thread.
__global__ __launch_bounds__(THREADS) void kl_partial(
        const float* __restrict__ pred, const float* __restrict__ truem,
        float* __restrict__ ws) {
    const int b   = blockIdx.x / BLOCKS_PER_BATCH;
    const int blk = blockIdx.x % BLOCKS_PER_BATCH;
    const size_t base = (size_t)b * NPB + (size_t)blk * CHUNK;

    const float4* p4 = (const float4*)(pred + base);
    const float4* t4 = (const float4*)(truem + base);

    float4 pr[V4_PER_THREAD], tr[V4_PER_THREAD];
    #pragma unroll
    for (int j = 0; j < V4_PER_THREAD; ++j) pr[j] = p4[threadIdx.x + j * THREADS];
    #pragma unroll
    for (int j = 0; j < V4_PER_THREAD; ++j) tr[j] = t4[threadIdx.x + j * THREADS];

    float sp = 0.f, st = 0.f, s = 0.f;
    #pragma unroll
    for (int j = 0; j < V4_PER_THREAD; ++j) {
        float4 p = pr[j];
        float4 t = tr[j];
        float px = p.x + EPS, py = p.y + EPS, pz = p.z + EPS, pw = p.w + EPS;
        float tx = t.x + EPS, ty = t.y + EPS, tz = t.z + EPS, tw = t.w + EPS;
        sp += (px + py) + (pz + pw);
        st += (tx + ty) + (tz + tw);
        s  += tx * (__logf(tx) - __logf(px));
        s  += ty * (__logf(ty) - __logf(py));
        s  += tz * (__logf(tz) - __logf(pz));
        s  += tw * (__logf(tw) - __logf(pw));
    }

    sp = waveReduce(sp);
    st = waveReduce(st);
    s  = waveReduce(s);

    __shared__ float red[3][THREADS / 64];
    const int wave = threadIdx.x >> 6;
    const int lane = threadIdx.x & 63;
    if (lane == 0) { red[0][wave] = sp; red[1][wave] = st; red[2][wave] = s; }
    __syncthreads();
    if (threadIdx.x == 0) {
        float a0 = 0.f, a1 = 0.f, a2 = 0.f;
        #pragma unroll
        for (int w = 0; w < THREADS / 64; ++w) {
            a0 += red[0][w]; a1 += red[1][w]; a2 += red[2][w];
        }
        // Unique slot per block: no atomics, no zero-init needed.
        ws[blockIdx.x]            = a0;   // Sp partial
        ws[NBLK + blockIdx.x]     = a1;   // St partial
        ws[2 * NBLK + blockIdx.x] = a2;   // S partial
    }
}

// Kernel 2: sum 32 partials per batch, combine, write mean KL.
__global__ __launch_bounds__(64) void kl_final(
        const float* __restrict__ ws, float* __restrict__ out) {
    const int b = threadIdx.x;   // 0..63, one wave, one batch per lane
    float Sp = 0.f, St = 0.f, S = 0.f;
    #pragma unroll
    for (int k = 0; k < BLOCKS_PER_BATCH; ++k) {
        const int idx = b * BLOCKS_PER_BATCH + k;
        Sp += ws[idx];
        St += ws[NBLK + idx];
        S  += ws[2 * NBLK + idx];
    }
    float kl = S / St + logf(Sp / St);
    kl = waveReduce(kl);
    if (b == 0) out[0] = kl * (1.0f / B);
}

extern "C" void kernel_launch(void* const* d_in, const int* in_sizes, int n_in,
                              void* d_out, int out_size, void* d_ws, size_t ws_size,
                              hipStream_t stream) {
    const float* pred  = (const float*)d_in[0];
    const float* truem = (const float*)d_in[1];
    float* out = (float*)d_out;
    float* ws  = (float*)d_ws;

    kl_partial<<<NBLK, THREADS, 0, stream>>>(pred, truem, ws);
    kl_final<<<1, 64, 0, stream>>>(ws, out);
}

// Round 4
// 144.872 us; speedup vs baseline: 1.0370x; 1.0092x over previous
//
#include <hip/hip_runtime.h>
#include <hip/hip_bf16.h>

#define EPS 1e-6f

constexpr int B = 64;
constexpr int NPB = 512 * 512;                     // elements per batch = 262144
constexpr int BLOCKS_PER_BATCH = 32;
constexpr int NBLK = B * BLOCKS_PER_BATCH;         // 2048 blocks total
constexpr int THREADS = 256;
constexpr int CHUNK = NPB / BLOCKS_PER_BATCH;      // 8192 elements per block
constexpr int V4_PER_THREAD = CHUNK / 4 / THREADS; // 8 float4 per thread per input

__device__ __forceinline__ float waveReduce(float v) {
    #pragma unroll
    for (int off = 32; off > 0; off >>= 1) v += __shfl_down(v, off, 64);
    return v;
}

// Kernel 1: per-block partial sums of (Sp, St, S = sum (t+e)*(log(t+e)-log(p+e))).
// sched_barrier(0) pins ALL 16 global_load_dwordx4 above the compute phase:
// 16 KB in flight per wave, hiding ~900-cyc HBM latency.
__global__ __launch_bounds__(THREADS) void kl_partial(
        const float* __restrict__ pred, const float* __restrict__ truem,
        float* __restrict__ ws) {
    const int b   = blockIdx.x / BLOCKS_PER_BATCH;
    const int blk = blockIdx.x % BLOCKS_PER_BATCH;
    const size_t base = (size_t)b * NPB + (size_t)blk * CHUNK;

    const float4* p4 = (const float4*)(pred + base);
    const float4* t4 = (const float4*)(truem + base);

    float4 pr[V4_PER_THREAD], tr[V4_PER_THREAD];
    #pragma unroll
    for (int j = 0; j < V4_PER_THREAD; ++j) pr[j] = p4[threadIdx.x + j * THREADS];
    #pragma unroll
    for (int j = 0; j < V4_PER_THREAD; ++j) tr[j] = t4[threadIdx.x + j * THREADS];

    // No instruction may cross this point: loads stay batched above.
    __builtin_amdgcn_sched_barrier(0);

    float sp = 0.f, st = 0.f, s = 0.f;
    #pragma unroll
    for (int j = 0; j < V4_PER_THREAD; ++j) {
        float4 p = pr[j];
        float4 t = tr[j];
        // raw sums; the +EPS contribution (NPB*EPS per batch) is folded in kl_final
        sp += (p.x + p.y) + (p.z + p.w);
        st += (t.x + t.y) + (t.z + t.w);
        float px = p.x + EPS, py = p.y + EPS, pz = p.z + EPS, pw = p.w + EPS;
        float tx = t.x + EPS, ty = t.y + EPS, tz = t.z + EPS, tw = t.w + EPS;
        s += tx * (__logf(tx) - __logf(px));
        s += ty * (__logf(ty) - __logf(py));
        s += tz * (__logf(tz) - __logf(pz));
        s += tw * (__logf(tw) - __logf(pw));
    }

    sp = waveReduce(sp);
    st = waveReduce(st);
    s  = waveReduce(s);

    __shared__ float red[3][THREADS / 64];
    const int wave = threadIdx.x >> 6;
    const int lane = threadIdx.x & 63;
    if (lane == 0) { red[0][wave] = sp; red[1][wave] = st; red[2][wave] = s; }
    __syncthreads();
    if (threadIdx.x == 0) {
        float a0 = 0.f, a1 = 0.f, a2 = 0.f;
        #pragma unroll
        for (int w = 0; w < THREADS / 64; ++w) {
            a0 += red[0][w]; a1 += red[1][w]; a2 += red[2][w];
        }
        // Unique slot per block: no atomics, no zero-init needed.
        ws[blockIdx.x]            = a0;   // Sp partial (without eps)
        ws[NBLK + blockIdx.x]     = a1;   // St partial (without eps)
        ws[2 * NBLK + blockIdx.x] = a2;   // S partial
    }
}

// Kernel 2: sum 32 partials per batch, add the analytic N*eps term, combine.
__global__ __launch_bounds__(64) void kl_final(
        const float* __restrict__ ws, float* __restrict__ out) {
    const int b = threadIdx.x;   // 0..63, one wave, one batch per lane
    float Sp = 0.f, St = 0.f, S = 0.f;
    #pragma unroll
    for (int k = 0; k < BLOCKS_PER_BATCH; ++k) {
        const int idx = b * BLOCKS_PER_BATCH + k;
        Sp += ws[idx];
        St += ws[NBLK + idx];
        S  += ws[2 * NBLK + idx];
    }
    const float epsN = (float)NPB * EPS;   // sum of the per-element +EPS
    Sp += epsN;
    St += epsN;
    float kl = S / St + logf(Sp / St);
    kl = waveReduce(kl);
    if (b == 0) out[0] = kl * (1.0f / B);
}

extern "C" void kernel_launch(void* const* d_in, const int* in_sizes, int n_in,
                              void* d_out, int out_size, void* d_ws, size_t ws_size,
                              hipStream_t stream) {
    const float* pred  = (const float*)d_in[0];
    const float* truem = (const float*)d_in[1];
    float* out = (float*)d_out;
    float* ws  = (float*)d_ws;

    kl_partial<<<NBLK, THREADS, 0, stream>>>(pred, truem, ws);
    kl_final<<<1, 64, 0, stream>>>(ws, out);
}

// Round 5
// 142.995 us; speedup vs baseline: 1.0506x; 1.0131x over previous
//
#include <hip/hip_runtime.h>
#include <hip/hip_bf16.h>

#define EPS 1e-6f

constexpr int B = 64;
constexpr int NPB = 512 * 512;                    // elements per batch = 262144
constexpr int CHUNK = 4096;                       // elements per block per array
constexpr int BLOCKS_PER_BATCH = NPB / CHUNK;     // 64
constexpr int NBLK = B * BLOCKS_PER_BATCH;        // 4096 blocks
constexpr int THREADS = 256;                      // 4 waves
constexpr int OPS_PER_WAVE = CHUNK / 256 / 4;     // 4 x 1KB staging ops per wave per array

__device__ __forceinline__ float waveReduce(float v) {
    #pragma unroll
    for (int off = 32; off > 0; off >>= 1) v += __shfl_down(v, off, 64);
    return v;
}

__device__ __forceinline__ void stage16(const float* g, float* l) {
    // lane i's 16B lands at LDS base + i*16 (wave-uniform base)
    __builtin_amdgcn_global_load_lds(
        (const __attribute__((address_space(1))) void*)g,
        (__attribute__((address_space(3))) void*)l, 16, 0, 0);
}

// Kernel 1: async-stage the block's 32KB chunk into LDS (deep DMA queue, no
// VGPR cost for in-flight loads), then compute partial (Sp, St, S) from LDS.
__global__ __launch_bounds__(THREADS) void kl_partial(
        const float* __restrict__ pred, const float* __restrict__ truem,
        float* __restrict__ ws) {
    __shared__ float lds_p[CHUNK];
    __shared__ float lds_t[CHUNK];

    // batches are contiguous: b*NPB + blk*CHUNK == blockIdx.x*CHUNK
    const size_t base = (size_t)blockIdx.x * CHUNK;
    const int wave = threadIdx.x >> 6;
    const int lane = threadIdx.x & 63;

    // Issue ALL staging ops before any wait: 8 x 1KB per wave in flight.
    #pragma unroll
    for (int j = 0; j < OPS_PER_WAVE; ++j) {
        const int blkoff = (wave * OPS_PER_WAVE + j) * 256;   // floats
        stage16(pred + base + blkoff + lane * 4, lds_p + blkoff);
    }
    #pragma unroll
    for (int j = 0; j < OPS_PER_WAVE; ++j) {
        const int blkoff = (wave * OPS_PER_WAVE + j) * 256;
        stage16(truem + base + blkoff + lane * 4, lds_t + blkoff);
    }
    __syncthreads();   // s_waitcnt vmcnt(0) + s_barrier: staging complete

    const float4* lp = (const float4*)lds_p;
    const float4* lt = (const float4*)lds_t;

    float sp = 0.f, st = 0.f, s = 0.f;
    #pragma unroll
    for (int j = 0; j < CHUNK / 4 / THREADS; ++j) {   // 4 ds_read_b128 pairs
        float4 p = lp[threadIdx.x + j * THREADS];
        float4 t = lt[threadIdx.x + j * THREADS];
        // raw sums; per-element +EPS folded analytically in kl_final
        sp += (p.x + p.y) + (p.z + p.w);
        st += (t.x + t.y) + (t.z + t.w);
        float px = p.x + EPS, py = p.y + EPS, pz = p.z + EPS, pw = p.w + EPS;
        float tx = t.x + EPS, ty = t.y + EPS, tz = t.z + EPS, tw = t.w + EPS;
        s += tx * (__logf(tx) - __logf(px));
        s += ty * (__logf(ty) - __logf(py));
        s += tz * (__logf(tz) - __logf(pz));
        s += tw * (__logf(tw) - __logf(pw));
    }

    sp = waveReduce(sp);
    st = waveReduce(st);
    s  = waveReduce(s);

    __shared__ float red[3][THREADS / 64];
    if (lane == 0) { red[0][wave] = sp; red[1][wave] = st; red[2][wave] = s; }
    __syncthreads();
    if (threadIdx.x == 0) {
        float a0 = 0.f, a1 = 0.f, a2 = 0.f;
        #pragma unroll
        for (int w = 0; w < THREADS / 64; ++w) {
            a0 += red[0][w]; a1 += red[1][w]; a2 += red[2][w];
        }
        ws[blockIdx.x]            = a0;   // Sp partial (without eps)
        ws[NBLK + blockIdx.x]     = a1;   // St partial (without eps)
        ws[2 * NBLK + blockIdx.x] = a2;   // S partial
    }
}

// Kernel 2: sum 64 partials per batch, add the analytic N*eps term, combine.
__global__ __launch_bounds__(64) void kl_final(
        const float* __restrict__ ws, float* __restrict__ out) {
    const int b = threadIdx.x;   // one wave, one batch per lane
    float Sp = 0.f, St = 0.f, S = 0.f;
    #pragma unroll 8
    for (int k = 0; k < BLOCKS_PER_BATCH; ++k) {
        const int idx = b * BLOCKS_PER_BATCH + k;
        Sp += ws[idx];
        St += ws[NBLK + idx];
        S  += ws[2 * NBLK + idx];
    }
    const float epsN = (float)NPB * EPS;   // sum of the per-element +EPS
    Sp += epsN;
    St += epsN;
    float kl = S / St + logf(Sp / St);
    kl = waveReduce(kl);
    if (b == 0) out[0] = kl * (1.0f / B);
}

extern "C" void kernel_launch(void* const* d_in, const int* in_sizes, int n_in,
                              void* d_out, int out_size, void* d_ws, size_t ws_size,
                              hipStream_t stream) {
    const float* pred  = (const float*)d_in[0];
    const float* truem = (const float*)d_in[1];
    float* out = (float*)d_out;
    float* ws  = (float*)d_ws;

    kl_partial<<<NBLK, THREADS, 0, stream>>>(pred, truem, ws);
    kl_final<<<1, 64, 0, stream>>>(ws, out);
}